// Round 2
// baseline (541.293 us; speedup 1.0000x reference)
//
#include <hip/hip_runtime.h>

// FGPM geometry features: 6 points (x,y) per row -> 15 dists, 20 angles(deg), 20 areas.
// Output layout: out[b*55 + f], f = [dist(15) | angle(20) | area(20)] in
// lexicographic pair/triplet order (i<j<k over 6 keys).
//
// Memory-bound: 96 MB in + 440 MB out (~536 MB total -> ~90 us floor at 6.3 TB/s).
// Strategy: 1 thread per row computes all 55 features into LDS (row stride 57 =
// odd -> conflict-free), then a coalesced LDS->global transpose write (55
// contiguous dword bursts per block). Output stores are nontemporal: the
// write-once stream shouldn't evict inputs from L2.

constexpr int T   = 128;   // threads per block; 2,000,000 % 128 == 0
constexpr int NF  = 55;    // features per row
constexpr int PAD = 57;    // LDS row stride (odd => conflict-free lane banks)

__global__ __launch_bounds__(T) void fgpm_kernel(
    const float2* __restrict__ p0, const float2* __restrict__ p1,
    const float2* __restrict__ p2, const float2* __restrict__ p3,
    const float2* __restrict__ p4, const float2* __restrict__ p5,
    float* __restrict__ out, int B)
{
    __shared__ float lds[T * PAD];
    const int tid = threadIdx.x;
    const long b  = (long)blockIdx.x * T + tid;

    float2 pt[6];
    if (b < (long)B) {
        pt[0] = p0[b]; pt[1] = p1[b]; pt[2] = p2[b];
        pt[3] = p3[b]; pt[4] = p4[b]; pt[5] = p5[b];
    } else {
        #pragma unroll
        for (int i = 0; i < 6; ++i) pt[i] = make_float2(0.f, 0.f);
    }

    float* row = &lds[tid * PAD];

    // ---- 15 pairwise distances ----
    {
        int idx = 0;
        #pragma unroll
        for (int i = 0; i < 6; ++i) {
            #pragma unroll
            for (int j = i + 1; j < 6; ++j) {
                float dx = pt[i].x - pt[j].x;
                float dy = pt[i].y - pt[j].y;
                row[idx++] = sqrtf(dx * dx + dy * dy);
            }
        }
    }

    // ---- 20 triplet angles (at middle vertex) + 20 areas ----
    {
        int t = 0;
        #pragma unroll
        for (int i = 0; i < 6; ++i) {
            #pragma unroll
            for (int j = i + 1; j < 6; ++j) {
                #pragma unroll
                for (int k = j + 1; k < 6; ++k) {
                    const float2 P1 = pt[i], P2 = pt[j], P3 = pt[k];
                    float v1x = P1.x - P2.x, v1y = P1.y - P2.y;
                    float v2x = P3.x - P2.x, v2y = P3.y - P2.y;
                    float dot = v1x * v2x + v1y * v2y;
                    float n1  = v1x * v1x + v1y * v1y;
                    float n2  = v2x * v2x + v2y * v2y;
                    float c   = dot / sqrtf(n1 * n2);
                    c = fminf(1.0f, fmaxf(-1.0f, c));
                    row[15 + t] = acosf(c) * 57.29577951308232f;  // degrees
                    float area = 0.5f * fabsf(P1.x * (P2.y - P3.y) +
                                              P2.x * (P3.y - P1.y) +
                                              P3.x * (P1.y - P2.y));
                    row[35 + t] = area;
                    ++t;
                }
            }
        }
    }

    __syncthreads();

    // ---- coalesced transpose write: block's output span is T*NF contiguous ----
    const long blk_start = (long)blockIdx.x * T;      // first row of this block
    long rows_left = (long)B - blk_start;
    const int nrows = rows_left > T ? T : (int)rows_left;
    const int total = nrows * NF;

    float* o = out + blk_start * NF;

    // flat output index g = tid + k*T; source lds addr = (g/NF)*PAD + g%NF,
    // maintained incrementally (T % NF == 18; step = (T/NF)*PAD + 18 == 132).
    constexpr int FSTEP = T % NF;                 // 18
    constexpr int ASTEP = (T / NF) * PAD + FSTEP; // 132
    int flat = tid;
    int f    = tid % NF;
    int addr = (tid / NF) * PAD + f;

    #pragma unroll 1
    for (int k = 0; k < NF; ++k) {
        if (flat < total) __builtin_nontemporal_store(lds[addr], &o[flat]);
        flat += T;
        f    += FSTEP;
        addr += ASTEP;
        if (f >= NF) { f -= NF; addr += (PAD - NF); }
    }
}

extern "C" void kernel_launch(void* const* d_in, const int* in_sizes, int n_in,
                              void* d_out, int out_size, void* d_ws, size_t ws_size,
                              hipStream_t stream) {
    const int B = in_sizes[0] / 2;   // inputs are (B, 2) float32
    const int grid = (B + T - 1) / T;
    fgpm_kernel<<<grid, dim3(T), 0, stream>>>(
        (const float2*)d_in[0], (const float2*)d_in[1], (const float2*)d_in[2],
        (const float2*)d_in[3], (const float2*)d_in[4], (const float2*)d_in[5],
        (float*)d_out, B);
}